// Round 1
// baseline (182.165 us; speedup 1.0000x reference)
//
#include <hip/hip_runtime.h>

typedef unsigned short u16t;
typedef unsigned int u32t;
typedef __bf16 bf16x8 __attribute__((ext_vector_type(8)));
typedef float f32x4 __attribute__((ext_vector_type(4)));
typedef unsigned int u32x4 __attribute__((ext_vector_type(4)));
typedef unsigned int u32x2 __attribute__((ext_vector_type(2)));

#define DEV static __device__ __forceinline__

DEV u16t f2bf(float f){
  u32t u = __builtin_bit_cast(u32t, f);
  u += 0x7fffu + ((u >> 16) & 1u);   // RNE
  return (u16t)(u >> 16);
}

DEV void gll16(const void* g, void* l){
  __builtin_amdgcn_global_load_lds((const __attribute__((address_space(1))) void*)g,
                                   (__attribute__((address_space(3))) void*)l, 16, 0, 0);
}

DEV f32x4 mfma16(bf16x8 a, bf16x8 b, f32x4 c){
  return __builtin_amdgcn_mfma_f32_16x16x32_bf16(a, b, c, 0, 0, 0);
}

// ---------------- cast x: fp32 -> bf16, 4 elems/thread ----------------
__global__ __launch_bounds__(256) void k_cast_x(const float4* __restrict__ x, u16t* __restrict__ xb){
  int idx = blockIdx.x * 256 + threadIdx.x;   // exactly 4096*256 = 1048576 float4s
  float4 v = x[idx];
  ushort4 o = make_ushort4(f2bf(v.x), f2bf(v.y), f2bf(v.z), f2bf(v.w));
  *(ushort4*)&xb[idx * 4] = o;
}

// ---------------- cast weights: Wqkv = [Wq*0.125 ; Wk ; Wv] bf16 [768][256], Wp bf16 ----------------
__global__ __launch_bounds__(256) void k_cast_w(const float* __restrict__ Wq, const float* __restrict__ Wk,
                         const float* __restrict__ Wv, const float* __restrict__ Wp,
                         u16t* __restrict__ wqkv, u16t* __restrict__ wp){
  int idx = blockIdx.x * 256 + threadIdx.x;  // 0..262143
  if (idx < 196608){
    float v;
    if (idx < 65536)        v = Wq[idx] * 0.125f;       // fold softmax scale into Wq
    else if (idx < 131072)  v = Wk[idx - 65536];
    else                    v = Wv[idx - 131072];
    wqkv[idx] = f2bf(v);
  } else {
    int j = idx - 196608;
    wp[j] = f2bf(Wp[j]);
  }
}

// ---------------- bf16 GEMM: out[m,n] = sum_k A[m,k]*W[n,k]  (A:[M][256], W:[Ntot][256]) ----------------
// BM=128, BN=64, BK=64, 4 waves (2x2). LDS 16B-chunk XOR swizzle: chunk' = chunk ^ (row&7).
template<bool IS_QKV>
__global__ __launch_bounds__(256) void k_gemm(const u16t* __restrict__ A, const u16t* __restrict__ W,
    const float* __restrict__ bias, u16t* __restrict__ oq, u16t* __restrict__ okk, u16t* __restrict__ ov,
    float* __restrict__ op, int Ntot){
  __shared__ u32x4 sm[1536];   // A: [0,1024) chunks (128 rows x 8), B: [1024,1536) (64 x 8)
  const int tid = threadIdx.x, lane = tid & 63, w = tid >> 6, g = lane >> 4, li = lane & 15;
  const int m0 = blockIdx.x * 128, n0 = blockIdx.y * 64;
  const int wm = w >> 1, wn = w & 1;
  f32x4 acc[4][2] = {};
  for (int kk = 0; kk < 4; ++kk){
    #pragma unroll
    for (int rnd = 0; rnd < 4; ++rnd){
      int cid = rnd * 256 + tid;
      int row = cid >> 3, ch = cid & 7;
      const u16t* src = A + (m0 + row) * 256 + kk * 64 + ((ch ^ (row & 7)) << 3);
      gll16(src, (char*)sm + (rnd * 256 + w * 64) * 16);
    }
    #pragma unroll
    for (int rnd = 0; rnd < 2; ++rnd){
      int cid = rnd * 256 + tid;
      int row = cid >> 3, ch = cid & 7;
      const u16t* src = W + (n0 + row) * 256 + kk * 64 + ((ch ^ (row & 7)) << 3);
      gll16(src, (char*)sm + 16384 + (rnd * 256 + w * 64) * 16);
    }
    __syncthreads();
    #pragma unroll
    for (int ks = 0; ks < 2; ++ks){
      bf16x8 bfr[2];
      #pragma unroll
      for (int nj = 0; nj < 2; ++nj){
        int row = wn * 32 + nj * 16 + li;
        bfr[nj] = __builtin_bit_cast(bf16x8, sm[1024 + row * 8 + ((ks * 4 + g) ^ (row & 7))]);
      }
      #pragma unroll
      for (int mi = 0; mi < 4; ++mi){
        int row = wm * 64 + mi * 16 + li;
        bf16x8 af = __builtin_bit_cast(bf16x8, sm[row * 8 + ((ks * 4 + g) ^ (row & 7))]);
        #pragma unroll
        for (int nj = 0; nj < 2; ++nj)
          acc[mi][nj] = mfma16(af, bfr[nj], acc[mi][nj]);
      }
    }
    __syncthreads();
  }
  if (IS_QKV){
    // block's 64 output cols live inside one (which, head): n0 multiple of 64
    const int which = n0 >> 8, h = (n0 >> 6) & 3;
    u16t* outp = which == 0 ? oq : (which == 1 ? okk : ov);
    #pragma unroll
    for (int mi = 0; mi < 4; ++mi){
      int m = m0 + wm * 64 + mi * 16 + g * 4;
      int b = m >> 12, nn = m & 4095;
      #pragma unroll
      for (int nj = 0; nj < 2; ++nj){
        int d = wn * 32 + nj * 16 + li;
        #pragma unroll
        for (int r = 0; r < 4; ++r)
          outp[((b * 4 + h) * 4096 + nn + r) * 64 + d] = f2bf(acc[mi][nj][r]);
      }
    }
  } else {
    #pragma unroll
    for (int mi = 0; mi < 4; ++mi){
      int m = m0 + wm * 64 + mi * 16 + g * 4;
      #pragma unroll
      for (int nj = 0; nj < 2; ++nj){
        int n = n0 + wn * 32 + nj * 16 + li;
        float bv = bias[n];
        #pragma unroll
        for (int r = 0; r < 4; ++r)
          op[(m + r) * Ntot + n] = acc[mi][nj][r] + bv;
      }
    }
  }
}

// ---------------- transpose V per head: v[bh][n][64] -> vt[bh][64][4096] ----------------
__global__ __launch_bounds__(256) void k_transpose_v(const u16t* __restrict__ v, u16t* __restrict__ vt){
  __shared__ u16t tl[64][72];
  const int n0 = blockIdx.x * 64, bh = blockIdx.y;
  const int tid = threadIdx.x;
  #pragma unroll
  for (int p = 0; p < 4; ++p){
    int idx = p * 256 + tid;
    int r = idx >> 4, c = idx & 15;
    ushort4 u = *(const ushort4*)&v[(bh * 4096 + n0 + r) * 64 + c * 4];
    tl[r][c*4+0] = u.x; tl[r][c*4+1] = u.y; tl[r][c*4+2] = u.z; tl[r][c*4+3] = u.w;
  }
  __syncthreads();
  #pragma unroll
  for (int p = 0; p < 4; ++p){
    int idx = p * 256 + tid;
    int d = idx >> 4, c = idx & 15;
    ushort4 u = make_ushort4(tl[c*4+0][d], tl[c*4+1][d], tl[c*4+2][d], tl[c*4+3][d]);
    *(ushort4*)&vt[(bh * 64 + d) * 4096 + n0 + c * 4] = u;
  }
}

// ---------------- flash attention ----------------
// grid 1024 = 16 bh x 64 q-tiles; 4 waves, each owns 16 q-rows. KV tile = 64.
// S^T = mfma(K, Q): lane holds S[i = lane&15][j = jt*16 + 4g + r]  (g = lane>>4)
// PV:  O^T = mfma(Vt, P^T): lane holds O[d = dt*16 + 4g + r][i = lane&15]
__global__ __launch_bounds__(256) void k_flash(const u16t* __restrict__ q, const u16t* __restrict__ kg,
    const u16t* __restrict__ vt, u16t* __restrict__ ao){
  __shared__ u32x4 sm[1536];  // K [0,512), Vt [512,1024), P per-wave [1024,1536)
  const int tid = threadIdx.x, lane = tid & 63, w = tid >> 6, g = lane >> 4, li = lane & 15;
  const int bh = blockIdx.x >> 6, qt = blockIdx.x & 63;
  const int qrow = qt * 64 + w * 16 + li;
  bf16x8 qf[2];
  #pragma unroll
  for (int ks = 0; ks < 2; ++ks)
    qf[ks] = __builtin_bit_cast(bf16x8, *(const u32x4*)&q[(bh * 4096 + qrow) * 64 + ks * 32 + g * 8]);
  f32x4 ot[4] = {};
  float mrun = -INFINITY, lrun = 0.f;
  const u16t* kbase = kg + bh * 4096 * 64;
  const u16t* vbase = vt + bh * 64 * 4096;
  #pragma unroll 1
  for (int t = 0; t < 64; ++t){
    #pragma unroll
    for (int rnd = 0; rnd < 2; ++rnd){
      int cid = rnd * 256 + tid;
      int row = cid >> 3, ch = cid & 7;
      gll16(kbase + (t * 64 + row) * 64 + ((ch ^ (row & 7)) << 3),
            (char*)sm + (rnd * 256 + w * 64) * 16);
      gll16(vbase + row * 4096 + t * 64 + ((ch ^ (row & 7)) << 3),
            (char*)sm + 8192 + (rnd * 256 + w * 64) * 16);
    }
    __syncthreads();
    // S^T: A = K rows (j), B = Q^T (cols i)
    f32x4 st[4] = {};
    #pragma unroll
    for (int ks = 0; ks < 2; ++ks){
      #pragma unroll
      for (int jt = 0; jt < 4; ++jt){
        int row = jt * 16 + li;
        bf16x8 kf = __builtin_bit_cast(bf16x8, sm[row * 8 + ((ks * 4 + g) ^ (row & 7))]);
        st[jt] = mfma16(kf, qf[ks], st[jt]);
      }
    }
    // online softmax over j (64 scores/row, row spread over lanes {i, i+16, i+32, i+48})
    float mt = -INFINITY;
    #pragma unroll
    for (int jt = 0; jt < 4; ++jt)
      #pragma unroll
      for (int r = 0; r < 4; ++r)
        mt = fmaxf(mt, st[jt][r]);
    mt = fmaxf(mt, __shfl_xor(mt, 16));
    mt = fmaxf(mt, __shfl_xor(mt, 32));
    float mnew = fmaxf(mrun, mt);
    float corr = __expf(mrun - mnew);   // exp(-inf)=0 on first tile
    float p[16];
    float ls = 0.f;
    #pragma unroll
    for (int jt = 0; jt < 4; ++jt)
      #pragma unroll
      for (int r = 0; r < 4; ++r){
        float e = __expf(st[jt][r] - mnew);
        p[jt * 4 + r] = e;
        ls += e;
      }
    ls += __shfl_xor(ls, 16);
    ls += __shfl_xor(ls, 32);
    lrun = lrun * corr + ls;
    mrun = mnew;
    #pragma unroll
    for (int dt = 0; dt < 4; ++dt)
      #pragma unroll
      for (int r = 0; r < 4; ++r)
        ot[dt][r] *= corr;
    // write P[i][j] (bf16, swizzled) — 4 values j = jt*16+4g+0..3 are contiguous -> one b64
    #pragma unroll
    for (int jt = 0; jt < 4; ++jt){
      u32x2 pk;
      pk.x = (u32t)f2bf(p[jt*4+0]) | ((u32t)f2bf(p[jt*4+1]) << 16);
      pk.y = (u32t)f2bf(p[jt*4+2]) | ((u32t)f2bf(p[jt*4+3]) << 16);
      int chj = 2 * jt + (g >> 1);
      *(u32x2*)((char*)sm + 16384 + w * 2048 + li * 128 + ((chj ^ (li & 7)) << 4) + ((g & 1) << 3)) = pk;
    }
    // PV: A = Vt rows (d), B = P^T (cols i)
    #pragma unroll
    for (int ks = 0; ks < 2; ++ks){
      bf16x8 pf = __builtin_bit_cast(bf16x8, sm[1024 + w * 128 + li * 8 + ((ks * 4 + g) ^ (li & 7))]);
      #pragma unroll
      for (int dt = 0; dt < 4; ++dt){
        int row = dt * 16 + li;
        bf16x8 vf = __builtin_bit_cast(bf16x8, sm[512 + row * 8 + ((ks * 4 + g) ^ (row & 7))]);
        ot[dt] = mfma16(vf, pf, ot[dt]);
      }
    }
    __syncthreads();
  }
  float inv = 1.f / lrun;
  const int b = bh >> 2, h = bh & 3;
  #pragma unroll
  for (int dt = 0; dt < 4; ++dt)
    #pragma unroll
    for (int r = 0; r < 4; ++r){
      int d = dt * 16 + g * 4 + r;
      ao[(b * 4096 + qrow) * 256 + h * 64 + d] = f2bf(ot[dt][r] * inv);
    }
}

extern "C" void kernel_launch(void* const* d_in, const int* in_sizes, int n_in,
                              void* d_out, int out_size, void* d_ws, size_t ws_size,
                              hipStream_t stream){
  (void)in_sizes; (void)n_in; (void)out_size; (void)ws_size;
  const float* x  = (const float*)d_in[0];
  const float* Wq = (const float*)d_in[1];
  const float* Wk = (const float*)d_in[2];
  const float* Wv = (const float*)d_in[3];
  const float* Wp = (const float*)d_in[4];
  const float* bp = (const float*)d_in[5];
  float* out = (float*)d_out;

  u16t* ws   = (u16t*)d_ws;              // all offsets in u16 elements
  u16t* xb   = ws;                       // [16384][256] bf16 x
  u16t* qg   = ws + 4194304;             // [16 bh][4096][64]
  u16t* kg   = ws + 8388608;
  u16t* vg   = ws + 12582912;
  u16t* vtg  = ws + 16777216;            // [16 bh][64][4096]
  u16t* ao   = ws + 20971520;            // [16384][256] attn out bf16
  u16t* wqkv = ws + 25165824;            // [768][256]
  u16t* wpb  = ws + 25362432;            // [256][256]

  k_cast_x<<<4096, 256, 0, stream>>>((const float4*)x, xb);
  k_cast_w<<<1024, 256, 0, stream>>>(Wq, Wk, Wv, Wp, wqkv, wpb);
  k_gemm<true><<<dim3(128, 12), 256, 0, stream>>>(xb, wqkv, nullptr, qg, kg, vg, nullptr, 768);
  k_transpose_v<<<dim3(64, 16), 256, 0, stream>>>(vg, vtg);
  k_flash<<<1024, 256, 0, stream>>>(qg, kg, vtg, ao);
  k_gemm<false><<<dim3(128, 4), 256, 0, stream>>>(ao, wpb, bp, nullptr, nullptr, nullptr, out, 256);
}

// Round 2
// 116.223 us; speedup vs baseline: 1.5674x; 1.5674x over previous
//
#include <hip/hip_runtime.h>

typedef unsigned short u16t;
typedef unsigned int u32t;
typedef __bf16 bf16x8 __attribute__((ext_vector_type(8)));
typedef __bf16 bf16x4 __attribute__((ext_vector_type(4)));
typedef float f32x4 __attribute__((ext_vector_type(4)));
typedef unsigned int u32x4 __attribute__((ext_vector_type(4)));
typedef unsigned int u32x2 __attribute__((ext_vector_type(2)));

#define DEV static __device__ __forceinline__

DEV u16t f2bf(float f){
  u32t u = __builtin_bit_cast(u32t, f);
  u += 0x7fffu + ((u >> 16) & 1u);   // RNE
  return (u16t)(u >> 16);
}

DEV u32t cvtpk(float lo, float hi){
  u32t r;
  asm("v_cvt_pk_bf16_f32 %0, %1, %2" : "=v"(r) : "v"(lo), "v"(hi));
  return r;
}

DEV float fexp2(float x){
#if __has_builtin(__builtin_amdgcn_exp2f)
  return __builtin_amdgcn_exp2f(x);
#else
  return exp2f(x);
#endif
}

DEV void gll16(const void* g, void* l){
  __builtin_amdgcn_global_load_lds((const __attribute__((address_space(1))) void*)g,
                                   (__attribute__((address_space(3))) void*)l, 16, 0, 0);
}

DEV f32x4 mfma16(bf16x8 a, bf16x8 b, f32x4 c){
  return __builtin_amdgcn_mfma_f32_16x16x32_bf16(a, b, c, 0, 0, 0);
}

// 16x16x16 bf16 MFMA via inline asm (A-frag layout k=4*(l>>4)+e matches the
// 16x16x32 C-layout j=4g+r -> P stays in registers, no LDS round-trip)
DEV f32x4 mfma16k16(bf16x4 a, bf16x4 b, f32x4 c){
  asm("v_mfma_f32_16x16x16_bf16 %0, %1, %2, %0" : "+v"(c) : "v"(a), "v"(b));
  return c;
}

// ---------------- cast x: fp32 -> bf16 ----------------
__global__ __launch_bounds__(256) void k_cast_x(const float4* __restrict__ x, u16t* __restrict__ xb){
  int idx = blockIdx.x * 256 + threadIdx.x;
  float4 v = x[idx];
  ushort4 o = make_ushort4(f2bf(v.x), f2bf(v.y), f2bf(v.z), f2bf(v.w));
  *(ushort4*)&xb[idx * 4] = o;
}

// ---------------- cast weights; fold 0.125*log2(e) into Wq (exp2-domain scores) ----------------
__global__ __launch_bounds__(256) void k_cast_w(const float* __restrict__ Wq, const float* __restrict__ Wk,
                         const float* __restrict__ Wv, const float* __restrict__ Wp,
                         u16t* __restrict__ wqkv, u16t* __restrict__ wp){
  int idx = blockIdx.x * 256 + threadIdx.x;  // 0..262143
  if (idx < 196608){
    float v;
    if (idx < 65536)        v = Wq[idx] * 0.1803368801f;   // 0.125 * log2(e)
    else if (idx < 131072)  v = Wk[idx - 65536];
    else                    v = Wv[idx - 131072];
    wqkv[idx] = f2bf(v);
  } else {
    int j = idx - 196608;
    wp[j] = f2bf(Wp[j]);
  }
}

// ---------------- bf16 GEMM: out[m,n] = sum_k A[m,k]*W[n,k] ----------------
// BM=128, BN=64, BK=64, 4 waves (2x2). LDS 16B-chunk XOR swizzle.
// QKV epilogue: Q,K -> [bh][n][64] row layout; V -> packed 16x16x16 B-fragments.
template<bool IS_QKV>
__global__ __launch_bounds__(256) void k_gemm(const u16t* __restrict__ A, const u16t* __restrict__ W,
    const float* __restrict__ bias, u16t* __restrict__ oq, u16t* __restrict__ okk, u16t* __restrict__ ov,
    float* __restrict__ op, int Ntot){
  __shared__ u32x4 sm[1536];
  const int tid = threadIdx.x, lane = tid & 63, w = tid >> 6, g = lane >> 4, li = lane & 15;
  const int m0 = blockIdx.x * 128, n0 = blockIdx.y * 64;
  const int wm = w >> 1, wn = w & 1;
  f32x4 acc[4][2] = {};
  for (int kk = 0; kk < 4; ++kk){
    #pragma unroll
    for (int rnd = 0; rnd < 4; ++rnd){
      int cid = rnd * 256 + tid;
      int row = cid >> 3, ch = cid & 7;
      const u16t* src = A + (m0 + row) * 256 + kk * 64 + ((ch ^ (row & 7)) << 3);
      gll16(src, (char*)sm + (rnd * 256 + w * 64) * 16);
    }
    #pragma unroll
    for (int rnd = 0; rnd < 2; ++rnd){
      int cid = rnd * 256 + tid;
      int row = cid >> 3, ch = cid & 7;
      const u16t* src = W + (n0 + row) * 256 + kk * 64 + ((ch ^ (row & 7)) << 3);
      gll16(src, (char*)sm + 16384 + (rnd * 256 + w * 64) * 16);
    }
    __syncthreads();
    #pragma unroll
    for (int ks = 0; ks < 2; ++ks){
      bf16x8 bfr[2];
      #pragma unroll
      for (int nj = 0; nj < 2; ++nj){
        int row = wn * 32 + nj * 16 + li;
        bfr[nj] = __builtin_bit_cast(bf16x8, sm[1024 + row * 8 + ((ks * 4 + g) ^ (row & 7))]);
      }
      #pragma unroll
      for (int mi = 0; mi < 4; ++mi){
        int row = wm * 64 + mi * 16 + li;
        bf16x8 af = __builtin_bit_cast(bf16x8, sm[row * 8 + ((ks * 4 + g) ^ (row & 7))]);
        #pragma unroll
        for (int nj = 0; nj < 2; ++nj)
          acc[mi][nj] = mfma16(af, bfr[nj], acc[mi][nj]);
      }
    }
    __syncthreads();
  }
  if (IS_QKV){
    const int which = n0 >> 8, h = (n0 >> 6) & 3;
    if (which == 2){
      // V: write packed B-fragments for 16x16x16 PV MFMA.
      // GEMM C-layout lane holds rows 4g+r, col li == fragment lane layout.
      #pragma unroll
      for (int mi = 0; mi < 4; ++mi){
        int m = m0 + wm * 64 + mi * 16;          // %16 == 0
        int b = m >> 12, jt = (m & 4095) >> 4;
        int bh = b * 4 + h;
        #pragma unroll
        for (int nj = 0; nj < 2; ++nj){
          int dt = wn * 2 + nj;
          u32x2 pk;
          pk.x = cvtpk(acc[mi][nj][0], acc[mi][nj][1]);
          pk.y = cvtpk(acc[mi][nj][2], acc[mi][nj][3]);
          *(u32x2*)((char*)ov + (size_t)(((bh * 256 + jt) * 4 + dt) * 512) + lane * 8) = pk;
        }
      }
    } else {
      u16t* outp = which == 0 ? oq : okk;
      #pragma unroll
      for (int mi = 0; mi < 4; ++mi){
        int m = m0 + wm * 64 + mi * 16 + g * 4;
        int b = m >> 12, nn = m & 4095;
        #pragma unroll
        for (int nj = 0; nj < 2; ++nj){
          int d = wn * 32 + nj * 16 + li;
          #pragma unroll
          for (int r = 0; r < 4; ++r)
            outp[((b * 4 + h) * 4096 + nn + r) * 64 + d] = f2bf(acc[mi][nj][r]);
        }
      }
    }
  } else {
    #pragma unroll
    for (int mi = 0; mi < 4; ++mi){
      int m = m0 + wm * 64 + mi * 16 + g * 4;
      #pragma unroll
      for (int nj = 0; nj < 2; ++nj){
        int n = n0 + wn * 32 + nj * 16 + li;
        float bv = bias[n];
        #pragma unroll
        for (int r = 0; r < 4; ++r)
          op[(m + r) * Ntot + n] = acc[mi][nj][r] + bv;
      }
    }
  }
}

// ---------------- flash attention (no-max exp2 softmax, denominator via MFMA) ----------------
// 512 blocks = 16 bh x 32 q-tiles(128 rows); 4 waves x 32 q-rows. KV tile 64.
// QK^T: S^T = mfma16x16x32(K, Q^T) -> lane holds S[i=li][j=jt*16+4g+r]
// P = exp2(S) in-register (cvt_pk) -> A-frag of mfma16x16x16
// PV: O = mfma16x16x16(P, Vfrag) -> lane holds O[i=4g+r][d=li]; lsum via B=ones.
__global__ __launch_bounds__(256, 2) void k_flash(const u16t* __restrict__ q,
    const u16t* __restrict__ kg, const u16t* __restrict__ vp, u16t* __restrict__ ao){
  __shared__ u32x4 sm[2048];   // K: [0,1024) (2 bufs x 512), Vfrag: [1024,2048)
  const int tid = threadIdx.x, lane = tid & 63, w = tid >> 6, g = lane >> 4, li = lane & 15;
  const int bid = blockIdx.x;
  const int swz = (bid & 7) * 64 + (bid >> 3);      // XCD-aware, bijective (512 % 8 == 0)
  const int bh = swz >> 5, qt = swz & 31;
  const int rowbase = qt * 128 + w * 32;
  bf16x8 qf[2][2];
  #pragma unroll
  for (int f = 0; f < 2; ++f)
    #pragma unroll
    for (int ks = 0; ks < 2; ++ks)
      qf[f][ks] = __builtin_bit_cast(bf16x8,
        *(const u32x4*)&q[(bh * 4096 + rowbase + f * 16 + li) * 64 + ks * 32 + g * 8]);
  f32x4 ot[2][4] = {};
  f32x4 ls[2] = {};
  const u16t* kbase = kg + bh * 262144;
  const char* vbase = (const char*)vp + (size_t)bh * 524288;
  const bf16x4 vone = __builtin_bit_cast(bf16x4, (u32x2){0x3F803F80u, 0x3F803F80u});

  auto stage = [&](int t, int c){
    #pragma unroll
    for (int rnd = 0; rnd < 2; ++rnd){
      int cid = rnd * 256 + tid, row = cid >> 3, ch = cid & 7;
      gll16(kbase + (t * 64 + row) * 64 + ((ch ^ (row & 7)) << 3),
            (char*)sm + c * 8192 + cid * 16);
      gll16(vbase + t * 8192 + cid * 16,
            (char*)sm + 16384 + c * 8192 + cid * 16);
    }
  };

  stage(0, 0);
  __syncthreads();
  int cur = 0;
  #pragma unroll 1
  for (int t = 0; t < 64; ++t){
    if (t < 63) stage(t + 1, cur ^ 1);
    const u32x4* kb = sm + cur * 512;
    const char* vb = (const char*)sm + 16384 + cur * 8192;
    // QK^T
    f32x4 st[2][4] = {};
    #pragma unroll
    for (int ks = 0; ks < 2; ++ks)
      #pragma unroll
      for (int jt = 0; jt < 4; ++jt){
        int row = jt * 16 + li;
        bf16x8 kf = __builtin_bit_cast(bf16x8, kb[row * 8 + ((ks * 4 + g) ^ (row & 7))]);
        st[0][jt] = mfma16(kf, qf[0][ks], st[0][jt]);
        st[1][jt] = mfma16(kf, qf[1][ks], st[1][jt]);
      }
    // P = exp2(S), packed to bf16 in-register
    bf16x4 pa[2][4];
    #pragma unroll
    for (int f = 0; f < 2; ++f)
      #pragma unroll
      for (int jt = 0; jt < 4; ++jt){
        u32x2 pk;
        pk.x = cvtpk(fexp2(st[f][jt][0]), fexp2(st[f][jt][1]));
        pk.y = cvtpk(fexp2(st[f][jt][2]), fexp2(st[f][jt][3]));
        pa[f][jt] = __builtin_bit_cast(bf16x4, pk);
      }
    // PV + denominator
    #pragma unroll
    for (int jt = 0; jt < 4; ++jt){
      #pragma unroll
      for (int dt = 0; dt < 4; ++dt){
        bf16x4 vf = *(const bf16x4*)(vb + (jt * 4 + dt) * 512 + lane * 8);
        ot[0][dt] = mfma16k16(pa[0][jt], vf, ot[0][dt]);
        ot[1][dt] = mfma16k16(pa[1][jt], vf, ot[1][dt]);
      }
      ls[0] = mfma16k16(pa[0][jt], vone, ls[0]);
      ls[1] = mfma16k16(pa[1][jt], vone, ls[1]);
    }
    __syncthreads();
    cur ^= 1;
  }
  const int b = bh >> 2, h = bh & 3;
  #pragma unroll
  for (int f = 0; f < 2; ++f){
    float inv[4];
    #pragma unroll
    for (int r = 0; r < 4; ++r)
      inv[r] = __builtin_amdgcn_rcpf(ls[f][r]);
    #pragma unroll
    for (int dt = 0; dt < 4; ++dt)
      #pragma unroll
      for (int r = 0; r < 4; ++r){
        int rowg = rowbase + f * 16 + 4 * g + r;
        ao[(b * 4096 + rowg) * 256 + h * 64 + dt * 16 + li] = f2bf(ot[f][dt][r] * inv[r]);
      }
  }
}

extern "C" void kernel_launch(void* const* d_in, const int* in_sizes, int n_in,
                              void* d_out, int out_size, void* d_ws, size_t ws_size,
                              hipStream_t stream){
  (void)in_sizes; (void)n_in; (void)out_size; (void)ws_size;
  const float* x  = (const float*)d_in[0];
  const float* Wq = (const float*)d_in[1];
  const float* Wk = (const float*)d_in[2];
  const float* Wv = (const float*)d_in[3];
  const float* Wp = (const float*)d_in[4];
  const float* bp = (const float*)d_in[5];
  float* out = (float*)d_out;

  u16t* ws   = (u16t*)d_ws;
  u16t* xb   = ws;                       // [16384][256] bf16 x
  u16t* qg   = ws + 4194304;             // [16 bh][4096][64]
  u16t* kg   = ws + 8388608;             // [16 bh][4096][64]
  u16t* vpk  = ws + 12582912;            // [16 bh][256 jt][4 dt][512B] packed V fragments
  u16t* ao   = ws + 16777216;            // [16384][256] attn out bf16
  u16t* wqkv = ws + 20971520;            // [768][256]
  u16t* wpb  = ws + 21168128;            // [256][256]

  k_cast_x<<<4096, 256, 0, stream>>>((const float4*)x, xb);
  k_cast_w<<<1024, 256, 0, stream>>>(Wq, Wk, Wv, Wp, wqkv, wpb);
  k_gemm<true><<<dim3(128, 12), 256, 0, stream>>>(xb, wqkv, nullptr, qg, kg, vpk, nullptr, 768);
  k_flash<<<512, 256, 0, stream>>>(qg, kg, vpk, ao);
  k_gemm<false><<<dim3(128, 4), 256, 0, stream>>>(ao, wpb, bp, nullptr, nullptr, nullptr, out, 256);
}

// Round 3
// 113.880 us; speedup vs baseline: 1.5996x; 1.0206x over previous
//
#include <hip/hip_runtime.h>

typedef unsigned short u16t;
typedef unsigned int u32t;
typedef __bf16 bf16x8 __attribute__((ext_vector_type(8)));
typedef float f32x4 __attribute__((ext_vector_type(4)));
typedef float f32x16 __attribute__((ext_vector_type(16)));
typedef unsigned int u32x4 __attribute__((ext_vector_type(4)));
typedef unsigned int u32x2 __attribute__((ext_vector_type(2)));

#define DEV static __device__ __forceinline__

DEV u16t f2bf(float f){
  u32t u = __builtin_bit_cast(u32t, f);
  u += 0x7fffu + ((u >> 16) & 1u);   // RNE
  return (u16t)(u >> 16);
}

DEV u32t cvtpk(float lo, float hi){
  u32t r;
  asm("v_cvt_pk_bf16_f32 %0, %1, %2" : "=v"(r) : "v"(lo), "v"(hi));
  return r;
}

// v_permlane32_swap_b32: a.hi32lanes <-> b.lo32lanes
// after: a[l] = l<32 ? a[l] : b[l-32];  b[l] = l<32 ? a_old[l+32] : b[l]
DEV void plswap(u32t &a, u32t &b){
  asm("v_permlane32_swap_b32 %0, %1" : "+v"(a), "+v"(b));
}

DEV float fexp2(float x){
#if __has_builtin(__builtin_amdgcn_exp2f)
  return __builtin_amdgcn_exp2f(x);
#else
  return exp2f(x);
#endif
}

DEV void gll16(const void* g, void* l){
  __builtin_amdgcn_global_load_lds((const __attribute__((address_space(1))) void*)g,
                                   (__attribute__((address_space(3))) void*)l, 16, 0, 0);
}

DEV f32x4 mfma16(bf16x8 a, bf16x8 b, f32x4 c){
  return __builtin_amdgcn_mfma_f32_16x16x32_bf16(a, b, c, 0, 0, 0);
}

DEV f32x16 mfma32(bf16x8 a, bf16x8 b, f32x16 c){
  return __builtin_amdgcn_mfma_f32_32x32x16_bf16(a, b, c, 0, 0, 0);
}

// ---------------- cast x: fp32 -> bf16 ----------------
__global__ __launch_bounds__(256) void k_cast_x(const float4* __restrict__ x, u16t* __restrict__ xb){
  int idx = blockIdx.x * 256 + threadIdx.x;
  float4 v = x[idx];
  ushort4 o = make_ushort4(f2bf(v.x), f2bf(v.y), f2bf(v.z), f2bf(v.w));
  *(ushort4*)&xb[idx * 4] = o;
}

// ---------------- cast weights; fold 0.125*log2(e) into Wq ----------------
__global__ __launch_bounds__(256) void k_cast_w(const float* __restrict__ Wq, const float* __restrict__ Wk,
                         const float* __restrict__ Wv, const float* __restrict__ Wp,
                         u16t* __restrict__ wqkv, u16t* __restrict__ wp){
  int idx = blockIdx.x * 256 + threadIdx.x;  // 0..262143
  if (idx < 196608){
    float v;
    if (idx < 65536)        v = Wq[idx] * 0.1803368801f;   // 0.125 * log2(e)
    else if (idx < 131072)  v = Wk[idx - 65536];
    else                    v = Wv[idx - 131072];
    wqkv[idx] = f2bf(v);
  } else {
    int j = idx - 196608;
    wp[j] = f2bf(Wp[j]);
  }
}

// ---------------- bf16 GEMM: out[m,n] = sum_k A[m,k]*W[n,k] ----------------
// BM=128, BN=64, BK=64, 4 waves (2x2). LDS 16B-chunk XOR swizzle.
// QKV epilogue: Q,K -> [bh][n][64]; V -> transposed [bh][64][4096] via LDS bounce.
template<bool IS_QKV>
__global__ __launch_bounds__(256) void k_gemm(const u16t* __restrict__ A, const u16t* __restrict__ W,
    const float* __restrict__ bias, u16t* __restrict__ oq, u16t* __restrict__ okk, u16t* __restrict__ vtg,
    float* __restrict__ op, int Ntot){
  __shared__ u32x4 sm[1536];
  const int tid = threadIdx.x, lane = tid & 63, w = tid >> 6, g = lane >> 4, li = lane & 15;
  const int m0 = blockIdx.x * 128, n0 = blockIdx.y * 64;
  const int wm = w >> 1, wn = w & 1;
  f32x4 acc[4][2] = {};
  for (int kk = 0; kk < 4; ++kk){
    #pragma unroll
    for (int rnd = 0; rnd < 4; ++rnd){
      int cid = rnd * 256 + tid;
      int row = cid >> 3, ch = cid & 7;
      const u16t* src = A + (m0 + row) * 256 + kk * 64 + ((ch ^ (row & 7)) << 3);
      gll16(src, (char*)sm + (rnd * 256 + w * 64) * 16);
    }
    #pragma unroll
    for (int rnd = 0; rnd < 2; ++rnd){
      int cid = rnd * 256 + tid;
      int row = cid >> 3, ch = cid & 7;
      const u16t* src = W + (n0 + row) * 256 + kk * 64 + ((ch ^ (row & 7)) << 3);
      gll16(src, (char*)sm + 16384 + (rnd * 256 + w * 64) * 16);
    }
    __syncthreads();
    #pragma unroll
    for (int ks = 0; ks < 2; ++ks){
      bf16x8 bfr[2];
      #pragma unroll
      for (int nj = 0; nj < 2; ++nj){
        int row = wn * 32 + nj * 16 + li;
        bfr[nj] = __builtin_bit_cast(bf16x8, sm[1024 + row * 8 + ((ks * 4 + g) ^ (row & 7))]);
      }
      #pragma unroll
      for (int mi = 0; mi < 4; ++mi){
        int row = wm * 64 + mi * 16 + li;
        bf16x8 af = __builtin_bit_cast(bf16x8, sm[row * 8 + ((ks * 4 + g) ^ (row & 7))]);
        #pragma unroll
        for (int nj = 0; nj < 2; ++nj)
          acc[mi][nj] = mfma16(af, bfr[nj], acc[mi][nj]);
      }
    }
    __syncthreads();
  }
  if (IS_QKV){
    const int which = n0 >> 8, h = (n0 >> 6) & 3;
    if (which == 2){
      // transpose V within block via LDS: produce vt[64 d][128 m] then store [bh][d][4096]
      u16t* smv = (u16t*)sm;
      #pragma unroll
      for (int mi = 0; mi < 4; ++mi){
        #pragma unroll
        for (int nj = 0; nj < 2; ++nj){
          int d = wn * 32 + nj * 16 + li;
          int mloc = wm * 64 + mi * 16 + g * 4;
          u32x2 pk2;
          pk2.x = cvtpk(acc[mi][nj][0], acc[mi][nj][1]);
          pk2.y = cvtpk(acc[mi][nj][2], acc[mi][nj][3]);
          int chk = mloc >> 3, inner = (mloc & 7) * 2;
          *(u32x2*)((char*)smv + d * 256 + (((chk ^ (d & 7))) << 4) + inner) = pk2;
        }
      }
      __syncthreads();
      const int b = m0 >> 12, bh2 = b * 4 + h, mbase = m0 & 4095;
      #pragma unroll
      for (int rnd = 0; rnd < 4; ++rnd){
        int qq = rnd * 256 + tid;       // 0..1023
        int d = qq >> 4, ch = qq & 15;
        *(u32x4*)&vtg[((size_t)bh2 * 64 + d) * 4096 + mbase + ch * 8] =
            *(const u32x4*)((char*)smv + d * 256 + ((ch ^ (d & 7)) << 4));
      }
    } else {
      u16t* outp = which == 0 ? oq : okk;
      #pragma unroll
      for (int mi = 0; mi < 4; ++mi){
        int m = m0 + wm * 64 + mi * 16 + g * 4;
        int b = m >> 12, nn = m & 4095;
        #pragma unroll
        for (int nj = 0; nj < 2; ++nj){
          int d = wn * 32 + nj * 16 + li;
          #pragma unroll
          for (int r = 0; r < 4; ++r)
            outp[((b * 4 + h) * 4096 + nn + r) * 64 + d] = f2bf(acc[mi][nj][r]);
        }
      }
    }
  } else {
    #pragma unroll
    for (int mi = 0; mi < 4; ++mi){
      int m = m0 + wm * 64 + mi * 16 + g * 4;
      #pragma unroll
      for (int nj = 0; nj < 2; ++nj){
        int n = n0 + wn * 32 + nj * 16 + li;
        float bv = bias[n];
        #pragma unroll
        for (int r = 0; r < 4; ++r)
          op[(m + r) * Ntot + n] = acc[mi][nj][r] + bv;
      }
    }
  }
}

// ---------------- flash attention, all 32x32x16 MFMA ----------------
// 512 blocks = 16 bh x 32 q-tiles(128 rows); 2 waves x 64 q-rows. KV tile 64.
// QK^T: S^T[j][i] = mfma32(K, Q^T); C-layout: lane(p=l&31,hi=l>>5) holds
//   S^T[j=(r&3)+8*(r>>2)+4hi + 32jt][i=p]. exp2 in-reg, pack via cvt_pk +
//   permlane32_swap into 32x32x16 B-frags (k=j). PV: O^T = mfma32(V^T, P^T).
// lsum: per-lane f32 partials over own j-half, combined once at end.
__global__ __launch_bounds__(128, 1) void k_flash(const u16t* __restrict__ q,
    const u16t* __restrict__ kg, const u16t* __restrict__ vtg, u16t* __restrict__ ao){
  __shared__ char sm[49152];   // K: 3 x 8KB @0; V^T: 3 x 8KB @24576
  const int tid = threadIdx.x, lane = tid & 63, w = tid >> 6;
  const int hi = lane >> 5, p = lane & 31;
  const int bid = blockIdx.x;
  const int swz = (bid & 7) * 64 + (bid >> 3);      // XCD-aware, bijective (512%8==0)
  const int bh = swz >> 5, qt = swz & 31;
  const int rowbase = qt * 128 + w * 64;
  const u16t* kb = kg + (size_t)bh * 262144;
  const u16t* vb = vtg + (size_t)bh * 262144;

  // Q B-frags: qf[it][kk]: lane holds Q[rowbase+it*32+p][k=kk*16+8hi+e]
  u32x4 qf[2][4];
  #pragma unroll
  for (int it = 0; it < 2; ++it)
    #pragma unroll
    for (int kk = 0; kk < 4; ++kk)
      qf[it][kk] = *(const u32x4*)&q[((size_t)bh * 4096 + rowbase + it * 32 + p) * 64 + kk * 16 + hi * 8];

  f32x16 ot[2][2] = {};      // [it][dt]
  float lsp[2][4] = {};      // per-lane lsum partials

  auto stage = [&](int t, int c){
    #pragma unroll
    for (int rnd = 0; rnd < 4; ++rnd){
      int cid = rnd * 128 + tid;        // 0..511
      int row = cid >> 3, ch = cid & 7;
      gll16(kb + (t * 64 + row) * 64 + ((ch ^ (row & 7)) << 3), sm + c * 8192 + cid * 16);
      gll16(vb + row * 4096 + t * 64 + ((ch ^ (row & 7)) << 3), sm + 24576 + c * 8192 + cid * 16);
    }
  };

  auto compute = [&](int cbuf){
    const char* kbuf = sm + cbuf * 8192;
    const char* vbuf = sm + 24576 + cbuf * 8192;
    // QK^T
    f32x16 st[2][2] = {};    // [it][jt]
    #pragma unroll
    for (int kk = 0; kk < 4; ++kk)
      #pragma unroll
      for (int jt = 0; jt < 2; ++jt){
        int row = jt * 32 + p;
        bf16x8 kf = __builtin_bit_cast(bf16x8,
            *(const u32x4*)(kbuf + row * 128 + (((kk * 2 + hi) ^ (row & 7)) << 4)));
        st[0][jt] = mfma32(kf, __builtin_bit_cast(bf16x8, qf[0][kk]), st[0][jt]);
        st[1][jt] = mfma32(kf, __builtin_bit_cast(bf16x8, qf[1][kk]), st[1][jt]);
      }
    // exp2 + lsum partials + pack to B-frags (k = j)
    u32x4 pf[2][2][2];       // [it][jt][s]
    #pragma unroll
    for (int it = 0; it < 2; ++it)
      #pragma unroll
      for (int jt = 0; jt < 2; ++jt){
        float e[16];
        #pragma unroll
        for (int r = 0; r < 16; ++r)
          e[r] = fexp2(st[it][jt][r]);
        #pragma unroll
        for (int r = 0; r < 16; ++r)
          lsp[it][r & 3] += e[r];
        #pragma unroll
        for (int s = 0; s < 2; ++s){
          u32t a0 = cvtpk(e[s*8+0], e[s*8+1]);
          u32t a1 = cvtpk(e[s*8+2], e[s*8+3]);
          u32t b0 = cvtpk(e[s*8+4], e[s*8+5]);
          u32t b1 = cvtpk(e[s*8+6], e[s*8+7]);
          plswap(a0, b0);    // a0 -> w0, b0 -> w2
          plswap(a1, b1);    // a1 -> w1, b1 -> w3
          pf[it][jt][s] = (u32x4){a0, a1, b0, b1};
        }
      }
    // PV: O^T[d][i] += V^T x P^T
    #pragma unroll
    for (int jt = 0; jt < 2; ++jt)
      #pragma unroll
      for (int s = 0; s < 2; ++s)
        #pragma unroll
        for (int dt = 0; dt < 2; ++dt){
          int row = dt * 32 + p;
          bf16x8 vf = __builtin_bit_cast(bf16x8,
              *(const u32x4*)(vbuf + row * 128 + ((((jt * 2 + s) * 2 + hi) ^ (row & 7)) << 4)));
          ot[0][dt] = mfma32(vf, __builtin_bit_cast(bf16x8, pf[0][jt][s]), ot[0][dt]);
          ot[1][dt] = mfma32(vf, __builtin_bit_cast(bf16x8, pf[1][jt][s]), ot[1][dt]);
        }
  };

  stage(0, 0);
  stage(1, 1);
  int c = 0;
  #pragma unroll 1
  for (int t = 0; t < 63; ++t){
    asm volatile("s_waitcnt vmcnt(8)" ::: "memory");
    __builtin_amdgcn_s_barrier();
    asm volatile("" ::: "memory");
    int nb = c + 2; if (nb > 2) nb -= 3;
    if (t < 62) stage(t + 2, nb);
    compute(c);
    c = (c == 2) ? 0 : c + 1;
  }
  asm volatile("s_waitcnt vmcnt(0)" ::: "memory");
  __builtin_amdgcn_s_barrier();
  asm volatile("" ::: "memory");
  compute(c);
  __syncthreads();   // protect LDS reuse in epilogue

  // lsum combine (partner lane l^32 holds the other j-half for same i)
  float inv[2];
  #pragma unroll
  for (int it = 0; it < 2; ++it){
    float l4 = (lsp[it][0] + lsp[it][1]) + (lsp[it][2] + lsp[it][3]);
    l4 += __shfl_xor(l4, 32);
    inv[it] = __builtin_amdgcn_rcpf(l4);
  }
  // transpose O^T -> O rows via per-wave LDS region, store coalesced
  char* smw = sm + w * 8192;   // [64 rows][128B] with 16B-chunk XOR swizzle
  #pragma unroll
  for (int it = 0; it < 2; ++it)
    #pragma unroll
    for (int dt = 0; dt < 2; ++dt)
      #pragma unroll
      for (int k2 = 0; k2 < 8; ++k2){
        int d0 = ((2*k2) & 3) + 8 * ((2*k2) >> 2) + 4 * hi + dt * 32;
        u32t pk = cvtpk(ot[it][dt][2*k2] * inv[it], ot[it][dt][2*k2+1] * inv[it]);
        int row = it * 32 + p;
        int colb = d0 * 2;
        *(u32t*)(smw + row * 128 + (((colb >> 4) ^ (row & 7)) << 4) + (colb & 15)) = pk;
      }
  const int b = bh >> 2, h = bh & 3;
  #pragma unroll
  for (int rnd = 0; rnd < 8; ++rnd){
    int qq = rnd * 64 + lane;        // 0..511
    int row = qq >> 3, ch = qq & 7;
    u32x4 v = *(const u32x4*)(smw + row * 128 + ((ch ^ (row & 7)) << 4));
    *(u32x4*)&ao[((size_t)b * 4096 + rowbase + row) * 256 + h * 64 + ch * 8] = v;
  }
}

extern "C" void kernel_launch(void* const* d_in, const int* in_sizes, int n_in,
                              void* d_out, int out_size, void* d_ws, size_t ws_size,
                              hipStream_t stream){
  (void)in_sizes; (void)n_in; (void)out_size; (void)ws_size;
  const float* x  = (const float*)d_in[0];
  const float* Wq = (const float*)d_in[1];
  const float* Wk = (const float*)d_in[2];
  const float* Wv = (const float*)d_in[3];
  const float* Wp = (const float*)d_in[4];
  const float* bp = (const float*)d_in[5];
  float* out = (float*)d_out;

  u16t* ws   = (u16t*)d_ws;
  u16t* xb   = ws;                       // [16384][256] bf16 x
  u16t* qg   = ws + 4194304;             // [16 bh][4096][64]
  u16t* kg   = ws + 8388608;             // [16 bh][4096][64]
  u16t* vtg  = ws + 12582912;            // [16 bh][64][4096] V^T
  u16t* ao   = ws + 16777216;            // [16384][256] attn out bf16
  u16t* wqkv = ws + 20971520;            // [768][256]
  u16t* wpb  = ws + 21168128;            // [256][256]

  k_cast_x<<<4096, 256, 0, stream>>>((const float4*)x, xb);
  k_cast_w<<<1024, 256, 0, stream>>>(Wq, Wk, Wv, Wp, wqkv, wpb);
  k_gemm<true><<<dim3(128, 12), 256, 0, stream>>>(xb, wqkv, nullptr, qg, kg, vtg, nullptr, 768);
  k_flash<<<512, 128, 0, stream>>>(qg, kg, vtg, ao);
  k_gemm<false><<<dim3(128, 4), 256, 0, stream>>>(ao, wpb, bp, nullptr, nullptr, nullptr, out, 256);
}

// Round 4
// 111.523 us; speedup vs baseline: 1.6334x; 1.0211x over previous
//
#include <hip/hip_runtime.h>

typedef unsigned short u16t;
typedef unsigned int u32t;
typedef __bf16 bf16x8 __attribute__((ext_vector_type(8)));
typedef float f32x4 __attribute__((ext_vector_type(4)));
typedef float f32x16 __attribute__((ext_vector_type(16)));
typedef unsigned int u32x4 __attribute__((ext_vector_type(4)));
typedef unsigned int u32x2 __attribute__((ext_vector_type(2)));

#define DEV static __device__ __forceinline__

DEV u16t f2bf(float f){
  u32t u = __builtin_bit_cast(u32t, f);
  u += 0x7fffu + ((u >> 16) & 1u);   // RNE
  return (u16t)(u >> 16);
}

DEV u32t cvtpk(float lo, float hi){
  u32t r;
  asm("v_cvt_pk_bf16_f32 %0, %1, %2" : "=v"(r) : "v"(lo), "v"(hi));
  return r;
}

// v_permlane32_swap_b32: a.hi32lanes <-> b.lo32lanes
DEV void plswap(u32t &a, u32t &b){
  asm("v_permlane32_swap_b32 %0, %1" : "+v"(a), "+v"(b));
}

DEV float fexp2(float x){
#if __has_builtin(__builtin_amdgcn_exp2f)
  return __builtin_amdgcn_exp2f(x);
#else
  return exp2f(x);
#endif
}

DEV void gll16(const void* g, void* l){
  __builtin_amdgcn_global_load_lds((const __attribute__((address_space(1))) void*)g,
                                   (__attribute__((address_space(3))) void*)l, 16, 0, 0);
}

DEV f32x4 mfma16(bf16x8 a, bf16x8 b, f32x4 c){
  return __builtin_amdgcn_mfma_f32_16x16x32_bf16(a, b, c, 0, 0, 0);
}

DEV f32x16 mfma32(bf16x8 a, bf16x8 b, f32x16 c){
  return __builtin_amdgcn_mfma_f32_32x32x16_bf16(a, b, c, 0, 0, 0);
}

// ---------------- cast x: fp32 -> bf16 ----------------
__global__ __launch_bounds__(256) void k_cast_x(const float4* __restrict__ x, u16t* __restrict__ xb){
  int idx = blockIdx.x * 256 + threadIdx.x;
  float4 v = x[idx];
  ushort4 o = make_ushort4(f2bf(v.x), f2bf(v.y), f2bf(v.z), f2bf(v.w));
  *(ushort4*)&xb[idx * 4] = o;
}

// ---------------- cast weights; fold 0.125*log2(e) into Wq ----------------
__global__ __launch_bounds__(256) void k_cast_w(const float* __restrict__ Wq, const float* __restrict__ Wk,
                         const float* __restrict__ Wv, const float* __restrict__ Wp,
                         u16t* __restrict__ wqkv, u16t* __restrict__ wp){
  int idx = blockIdx.x * 256 + threadIdx.x;  // 0..262143
  if (idx < 196608){
    float v;
    if (idx < 65536)        v = Wq[idx] * 0.1803368801f;   // 0.125 * log2(e)
    else if (idx < 131072)  v = Wk[idx - 65536];
    else                    v = Wv[idx - 131072];
    wqkv[idx] = f2bf(v);
  } else {
    int j = idx - 196608;
    wp[j] = f2bf(Wp[j]);
  }
}

// ---------------- bf16 GEMM: out[m,n] = sum_k A[m,k]*W[n,k] ----------------
// BM=128, BN=64, BK=64, 4 waves (2x2). LDS 16B-chunk XOR swizzle.
// QKV epilogue: Q,K -> [bh][n][64]; V -> transposed [bh][64][4096] via LDS bounce.
template<bool IS_QKV>
__global__ __launch_bounds__(256) void k_gemm(const u16t* __restrict__ A, const u16t* __restrict__ W,
    const float* __restrict__ bias, u16t* __restrict__ oq, u16t* __restrict__ okk, u16t* __restrict__ vtg,
    float* __restrict__ op, int Ntot){
  __shared__ u32x4 sm[1536];
  const int tid = threadIdx.x, lane = tid & 63, w = tid >> 6, g = lane >> 4, li = lane & 15;
  const int m0 = blockIdx.x * 128, n0 = blockIdx.y * 64;
  const int wm = w >> 1, wn = w & 1;
  f32x4 acc[4][2] = {};
  for (int kk = 0; kk < 4; ++kk){
    #pragma unroll
    for (int rnd = 0; rnd < 4; ++rnd){
      int cid = rnd * 256 + tid;
      int row = cid >> 3, ch = cid & 7;
      const u16t* src = A + (m0 + row) * 256 + kk * 64 + ((ch ^ (row & 7)) << 3);
      gll16(src, (char*)sm + (rnd * 256 + w * 64) * 16);
    }
    #pragma unroll
    for (int rnd = 0; rnd < 2; ++rnd){
      int cid = rnd * 256 + tid;
      int row = cid >> 3, ch = cid & 7;
      const u16t* src = W + (n0 + row) * 256 + kk * 64 + ((ch ^ (row & 7)) << 3);
      gll16(src, (char*)sm + 16384 + (rnd * 256 + w * 64) * 16);
    }
    __syncthreads();
    #pragma unroll
    for (int ks = 0; ks < 2; ++ks){
      bf16x8 bfr[2];
      #pragma unroll
      for (int nj = 0; nj < 2; ++nj){
        int row = wn * 32 + nj * 16 + li;
        bfr[nj] = __builtin_bit_cast(bf16x8, sm[1024 + row * 8 + ((ks * 4 + g) ^ (row & 7))]);
      }
      #pragma unroll
      for (int mi = 0; mi < 4; ++mi){
        int row = wm * 64 + mi * 16 + li;
        bf16x8 af = __builtin_bit_cast(bf16x8, sm[row * 8 + ((ks * 4 + g) ^ (row & 7))]);
        #pragma unroll
        for (int nj = 0; nj < 2; ++nj)
          acc[mi][nj] = mfma16(af, bfr[nj], acc[mi][nj]);
      }
    }
    __syncthreads();
  }
  if (IS_QKV){
    const int which = n0 >> 8, h = (n0 >> 6) & 3;
    if (which == 2){
      // transpose V within block via LDS: produce vt[64 d][128 m] then store [bh][d][4096]
      u16t* smv = (u16t*)sm;
      #pragma unroll
      for (int mi = 0; mi < 4; ++mi){
        #pragma unroll
        for (int nj = 0; nj < 2; ++nj){
          int d = wn * 32 + nj * 16 + li;
          int mloc = wm * 64 + mi * 16 + g * 4;
          u32x2 pk2;
          pk2.x = cvtpk(acc[mi][nj][0], acc[mi][nj][1]);
          pk2.y = cvtpk(acc[mi][nj][2], acc[mi][nj][3]);
          int chk = mloc >> 3, inner = (mloc & 7) * 2;
          *(u32x2*)((char*)smv + d * 256 + (((chk ^ (d & 7))) << 4) + inner) = pk2;
        }
      }
      __syncthreads();
      const int b = m0 >> 12, bh2 = b * 4 + h, mbase = m0 & 4095;
      #pragma unroll
      for (int rnd = 0; rnd < 4; ++rnd){
        int qq = rnd * 256 + tid;       // 0..1023
        int d = qq >> 4, ch = qq & 15;
        *(u32x4*)&vtg[((size_t)bh2 * 64 + d) * 4096 + mbase + ch * 8] =
            *(const u32x4*)((char*)smv + d * 256 + ((ch ^ (d & 7)) << 4));
      }
    } else {
      u16t* outp = which == 0 ? oq : okk;
      #pragma unroll
      for (int mi = 0; mi < 4; ++mi){
        int m = m0 + wm * 64 + mi * 16 + g * 4;
        int b = m >> 12, nn = m & 4095;
        #pragma unroll
        for (int nj = 0; nj < 2; ++nj){
          int d = wn * 32 + nj * 16 + li;
          #pragma unroll
          for (int r = 0; r < 4; ++r)
            outp[((b * 4 + h) * 4096 + nn + r) * 64 + d] = f2bf(acc[mi][nj][r]);
        }
      }
    }
  } else {
    #pragma unroll
    for (int mi = 0; mi < 4; ++mi){
      int m = m0 + wm * 64 + mi * 16 + g * 4;
      #pragma unroll
      for (int nj = 0; nj < 2; ++nj){
        int n = n0 + wn * 32 + nj * 16 + li;
        float bv = bias[n];
        #pragma unroll
        for (int r = 0; r < 4; ++r)
          op[(m + r) * Ntot + n] = acc[mi][nj][r] + bv;
      }
    }
  }
}

// ---------------- flash attention, all 32x32x16 MFMA, in-block KV split ----------------
// 1024 blocks = 16 bh x 64 q-tiles(64 rows); 2 waves share the q-rows, each owns
// HALF the KV range (2048 rows = 32 tiles of 64) with a PRIVATE single-buffered
// LDS tile (16KB/wave) -> no barriers in the main loop; counted vmcnt(8) with
// split K/V staging gives each load ~a full phase of flight. No-max exp2 softmax
// => merge is O = O0+O1, l = l0+l1 via LDS once per block.
__global__ __launch_bounds__(128, 2) void k_flash(const u16t* __restrict__ q,
    const u16t* __restrict__ kg, const u16t* __restrict__ vtg, u16t* __restrict__ ao){
  __shared__ u32x4 sm4[2080];   // wave w: [w*16KB, +8KB) K, [+8KB, +16KB) V; lsums @32768
  char* sm = (char*)sm4;
  const int tid = threadIdx.x, lane = tid & 63, w = tid >> 6;
  const int hi = lane >> 5, p = lane & 31;
  const int bid = blockIdx.x;
  const int swz = (bid & 7) * 128 + (bid >> 3);   // XCD-aware, bijective (1024%8==0)
  const int bh = swz >> 6, qt = swz & 63;
  const int rowbase = qt * 64;
  const u16t* kb = kg + (size_t)bh * 262144 + (size_t)w * 2048 * 64;  // wave's kv half
  const u16t* vb = vtg + (size_t)bh * 262144 + w * 2048;              // V^T col offset
  char* Kb = sm + w * 16384;
  char* Vb = Kb + 8192;

  // Q B-frags: qf[it][kk]: lane holds Q[rowbase+it*32+p][k=kk*16+8hi+e]
  u32x4 qf[2][4];
  #pragma unroll
  for (int it = 0; it < 2; ++it)
    #pragma unroll
    for (int kk = 0; kk < 4; ++kk)
      qf[it][kk] = *(const u32x4*)&q[((size_t)bh * 4096 + rowbase + it * 32 + p) * 64 + kk * 16 + hi * 8];

  f32x16 ot[2][2] = {};      // [it][dt]
  float lsp[2][4] = {};      // per-lane lsum partials

  auto stageK = [&](int t){
    #pragma unroll
    for (int i = 0; i < 8; ++i){
      int cid = i * 64 + lane;          // 0..511
      int row = cid >> 3, ch = cid & 7;
      gll16(kb + (t * 64 + row) * 64 + ((ch ^ (row & 7)) << 3), Kb + cid * 16);
    }
  };
  auto stageV = [&](int t){
    #pragma unroll
    for (int i = 0; i < 8; ++i){
      int cid = i * 64 + lane;
      int row = cid >> 3, ch = cid & 7;   // row = d
      gll16(vb + row * 4096 + t * 64 + ((ch ^ (row & 7)) << 3), Vb + cid * 16);
    }
  };

  stageK(0);
  stageV(0);
  #pragma unroll 1
  for (int t = 0; t < 32; ++t){
    asm volatile("s_waitcnt vmcnt(8)" ::: "memory");   // K(t) landed
    // QK^T
    f32x16 st[2][2] = {};    // [it][jt]
    #pragma unroll
    for (int kk = 0; kk < 4; ++kk)
      #pragma unroll
      for (int jt = 0; jt < 2; ++jt){
        int row = jt * 32 + p;
        bf16x8 kf = __builtin_bit_cast(bf16x8,
            *(const u32x4*)(Kb + row * 128 + (((kk * 2 + hi) ^ (row & 7)) << 4)));
        st[0][jt] = mfma32(kf, __builtin_bit_cast(bf16x8, qf[0][kk]), st[0][jt]);
        st[1][jt] = mfma32(kf, __builtin_bit_cast(bf16x8, qf[1][kk]), st[1][jt]);
      }
    asm volatile("s_waitcnt lgkmcnt(0)" ::: "memory"); // K-reads retired before overwrite
    stageK((t + 1) & 31);                              // t=31 wraps: harmless dummy reload
    // exp2 + lsum partials + pack to B-frags (k = j)
    u32x4 pf[2][2][2];       // [it][jt][s]
    #pragma unroll
    for (int it = 0; it < 2; ++it)
      #pragma unroll
      for (int jt = 0; jt < 2; ++jt){
        float e[16];
        #pragma unroll
        for (int r = 0; r < 16; ++r)
          e[r] = fexp2(st[it][jt][r]);
        #pragma unroll
        for (int r = 0; r < 16; ++r)
          lsp[it][r & 3] += e[r];
        #pragma unroll
        for (int s = 0; s < 2; ++s){
          u32t a0 = cvtpk(e[s*8+0], e[s*8+1]);
          u32t a1 = cvtpk(e[s*8+2], e[s*8+3]);
          u32t b0 = cvtpk(e[s*8+4], e[s*8+5]);
          u32t b1 = cvtpk(e[s*8+6], e[s*8+7]);
          plswap(a0, b0);
          plswap(a1, b1);
          pf[it][jt][s] = (u32x4){a0, a1, b0, b1};
        }
      }
    asm volatile("s_waitcnt vmcnt(8)" ::: "memory");   // V(t) landed (K(t+1) in flight)
    // PV: O^T[d][i] += V^T x P^T
    #pragma unroll
    for (int jt = 0; jt < 2; ++jt)
      #pragma unroll
      for (int s = 0; s < 2; ++s)
        #pragma unroll
        for (int dt = 0; dt < 2; ++dt){
          int row = dt * 32 + p;
          bf16x8 vf = __builtin_bit_cast(bf16x8,
              *(const u32x4*)(Vb + row * 128 + ((((jt * 2 + s) * 2 + hi) ^ (row & 7)) << 4)));
          ot[0][dt] = mfma32(vf, __builtin_bit_cast(bf16x8, pf[0][jt][s]), ot[0][dt]);
          ot[1][dt] = mfma32(vf, __builtin_bit_cast(bf16x8, pf[1][jt][s]), ot[1][dt]);
        }
    asm volatile("s_waitcnt lgkmcnt(0)" ::: "memory"); // V-reads retired before overwrite
    stageV((t + 1) & 31);
  }
  asm volatile("s_waitcnt vmcnt(0) lgkmcnt(0)" ::: "memory");  // drain dummy stages

  // lsum per wave: combine 4 partials + hi halves -> lane p holds l[it] for row it*32+p
  float l4[2];
  #pragma unroll
  for (int it = 0; it < 2; ++it){
    float v = (lsp[it][0] + lsp[it][1]) + (lsp[it][2] + lsp[it][3]);
    v += __shfl_xor(v, 32);
    l4[it] = v;
  }
  __syncthreads();   // both waves done with their K/V buffers

  // write O-partials as [it][q 32][d 64] f32 into own 16KB region (quad-XOR swizzle)
  char* reg = sm + w * 16384;
  #pragma unroll
  for (int it = 0; it < 2; ++it)
    #pragma unroll
    for (int dt = 0; dt < 2; ++dt)
      #pragma unroll
      for (int s = 0; s < 4; ++s){
        f32x4 v4 = {ot[it][dt][4*s+0], ot[it][dt][4*s+1], ot[it][dt][4*s+2], ot[it][dt][4*s+3]};
        int quad = 2 * s + hi + 8 * dt;              // d0/4, d0 = 8s+4hi+32dt
        *(f32x4*)(reg + it * 8192 + p * 256 + ((quad ^ (p & 15)) << 4)) = v4;
      }
  // lsums exchange: [wave][it][q]
  float* lsums = (float*)(sm + 32768);
  if (lane < 32){
    lsums[(w * 2 + 0) * 32 + lane] = l4[0];
    lsums[(w * 2 + 1) * 32 + lane] = l4[1];
  }
  __syncthreads();

  // merge: wave w finalizes rows it=w: O = P0 + P1, * 1/(l0+l1); store row-major
  {
    const int qloc = lane >> 1, dh = lane & 1;       // q in [0,32), d-half
    float ltot = lsums[(0 * 2 + w) * 32 + qloc] + lsums[(1 * 2 + w) * 32 + qloc];
    float inv = __builtin_amdgcn_rcpf(ltot);
    const int b = bh >> 2, h = bh & 3;
    u16t* dst = ao + ((size_t)b * 4096 + rowbase + w * 32 + qloc) * 256 + h * 64 + dh * 32;
    u32t pk[16];
    #pragma unroll
    for (int k = 0; k < 8; ++k){
      int quad = dh * 8 + k;
      f32x4 a = *(const f32x4*)(sm + 0 * 16384 + w * 8192 + qloc * 256 + ((quad ^ (qloc & 15)) << 4));
      f32x4 c = *(const f32x4*)(sm + 1 * 16384 + w * 8192 + qloc * 256 + ((quad ^ (qloc & 15)) << 4));
      f32x4 o = (a + c) * inv;
      pk[2*k]   = cvtpk(o[0], o[1]);
      pk[2*k+1] = cvtpk(o[2], o[3]);
    }
    #pragma unroll
    for (int k = 0; k < 4; ++k)
      *(u32x4*)(dst + k * 8) = (u32x4){pk[4*k], pk[4*k+1], pk[4*k+2], pk[4*k+3]};
  }
}

extern "C" void kernel_launch(void* const* d_in, const int* in_sizes, int n_in,
                              void* d_out, int out_size, void* d_ws, size_t ws_size,
                              hipStream_t stream){
  (void)in_sizes; (void)n_in; (void)out_size; (void)ws_size;
  const float* x  = (const float*)d_in[0];
  const float* Wq = (const float*)d_in[1];
  const float* Wk = (const float*)d_in[2];
  const float* Wv = (const float*)d_in[3];
  const float* Wp = (const float*)d_in[4];
  const float* bp = (const float*)d_in[5];
  float* out = (float*)d_out;

  u16t* ws   = (u16t*)d_ws;
  u16t* xb   = ws;                       // [16384][256] bf16 x
  u16t* qg   = ws + 4194304;             // [16 bh][4096][64]
  u16t* kg   = ws + 8388608;             // [16 bh][4096][64]
  u16t* vtg  = ws + 12582912;            // [16 bh][64][4096] V^T
  u16t* ao   = ws + 16777216;            // [16384][256] attn out bf16
  u16t* wqkv = ws + 20971520;            // [768][256]
  u16t* wpb  = ws + 21168128;            // [256][256]

  k_cast_x<<<4096, 256, 0, stream>>>((const float4*)x, xb);
  k_cast_w<<<1024, 256, 0, stream>>>(Wq, Wk, Wv, Wp, wqkv, wpb);
  k_gemm<true><<<dim3(128, 12), 256, 0, stream>>>(xb, wqkv, nullptr, qg, kg, vtg, nullptr, 768);
  k_flash<<<1024, 128, 0, stream>>>(qg, kg, vtg, ao);
  k_gemm<false><<<dim3(128, 4), 256, 0, stream>>>(ao, wpb, bp, nullptr, nullptr, nullptr, out, 256);
}